// Round 7
// baseline (7580.724 us; speedup 1.0000x reference)
//
#include <hip/hip_runtime.h>
#include <math.h>
#include <cstddef>

#define N_PTS 131072
#define SDIM  512
#define D1    513

static constexpr int NITER = 100;
static constexpr int BLK   = 512;            // 8 waves / block
static constexpr int GRID  = 512;            // 2 blocks / CU
static constexpr int WPB   = BLK / 64;       // 8 waves per block
static constexpr int NW    = GRID * WPB;     // 4096 waves
static constexpr int NPAIR = N_PTS / 2;      // 65536 row-pairs
static constexpr int PPW   = NPAIR / NW;     // 16 pairs per wave

typedef float f32x4 __attribute__((ext_vector_type(4)));

struct Ws {
  unsigned int ticket;
  unsigned int pad[3];
  double colsum[514];          // [0..511] spatial, [512] t-sum, [513] cc-sum
  double part[514][GRID];      // column-major per-block partials
  float  mean[513];            // [0] = time coordinate
};

// ---------------- streaming kernel (R4 structure + nt stream-set) ----------------
// Stream set = pairs with (physical_pair & 7) == 7 (1/8 of data, 33.5 MB):
// loaded non-temporally so the kept 234.9 MB fits the 256 MB Infinity Cache.
template<bool INIT>
__global__ __launch_bounds__(BLK, 4)
void big_kernel(const float* __restrict__ data, Ws* __restrict__ ws, int rev)
{
  const int l    = threadIdx.x & 63;
  const int sl   = l & 31;       // lane within half
  const int half = l >> 5;       // 0: even row of pair, 1: odd row
  const int wid  = threadIdx.x >> 6;
  const int gw   = blockIdx.x * WPB + wid;   // 0..NW-1

  float  m0 = 0.f;
  float4 mk0 = {0,0,0,0}, mk1 = {0,0,0,0}, mk2 = {0,0,0,0}, mk3 = {0,0,0,0};
  if constexpr (!INIT) {
    m0 = ws->mean[0];
    const float4* mp = (const float4*)(ws->mean + 1);
    mk0 = mp[0*32 + sl]; mk1 = mp[1*32 + sl];
    mk2 = mp[2*32 + sl]; mk3 = mp[3*32 + sl];
  }

  // 16 f64 accumulators per lane; lane covers cols (j*32+sl)*4 + i
  double acc[4][4] = {};
  double acc_t = 0.0, acc_cc = 0.0;

  const int p0 = gw * PPW;

#define LDPAIR(d0, d1, d2, d3, p) do {                                        \
    int pr_ = rev ? (NPAIR - 1 - (p)) : (p);                                  \
    const f32x4* b_ = (const f32x4*)(data + (size_t)(2 * pr_ + half) * SDIM); \
    if ((pr_ & 7) == 7) {                                                     \
      d0 = __builtin_nontemporal_load(b_ + 0*32 + sl);                        \
      d1 = __builtin_nontemporal_load(b_ + 1*32 + sl);                        \
      d2 = __builtin_nontemporal_load(b_ + 2*32 + sl);                        \
      d3 = __builtin_nontemporal_load(b_ + 3*32 + sl);                        \
    } else {                                                                  \
      d0 = b_[0*32 + sl]; d1 = b_[1*32 + sl];                                 \
      d2 = b_[2*32 + sl]; d3 = b_[3*32 + sl];                                 \
    }                                                                         \
  } while (0)

  f32x4 c0, c1v, c2, c3, n0, n1, n2, n3;
  LDPAIR(c0, c1v, c2, c3, p0);

  for (int k = 0; k < PPW; ++k) {
    const bool hasnext = (k + 1 < PPW);
    if (hasnext) LDPAIR(n0, n1, n2, n3, p0 + k + 1);

    // tree-shaped per-lane partial sums (shorter dependent chains)
    float sqa = c0.x * c0.x;
    sqa = fmaf(c0.y, c0.y, sqa); sqa = fmaf(c0.z, c0.z, sqa); sqa = fmaf(c0.w, c0.w, sqa);
    sqa = fmaf(c1v.x, c1v.x, sqa); sqa = fmaf(c1v.y, c1v.y, sqa);
    sqa = fmaf(c1v.z, c1v.z, sqa); sqa = fmaf(c1v.w, c1v.w, sqa);
    float sqb = c2.x * c2.x;
    sqb = fmaf(c2.y, c2.y, sqb); sqb = fmaf(c2.z, c2.z, sqb); sqb = fmaf(c2.w, c2.w, sqb);
    sqb = fmaf(c3.x, c3.x, sqb); sqb = fmaf(c3.y, c3.y, sqb);
    sqb = fmaf(c3.z, c3.z, sqb); sqb = fmaf(c3.w, c3.w, sqb);
    float sq = sqa + sqb;

    float dot = 0.f;
    if constexpr (!INIT) {
      float da = c0.x * mk0.x;
      da = fmaf(c0.y, mk0.y, da); da = fmaf(c0.z, mk0.z, da); da = fmaf(c0.w, mk0.w, da);
      da = fmaf(c1v.x, mk1.x, da); da = fmaf(c1v.y, mk1.y, da);
      da = fmaf(c1v.z, mk1.z, da); da = fmaf(c1v.w, mk1.w, da);
      float db = c2.x * mk2.x;
      db = fmaf(c2.y, mk2.y, db); db = fmaf(c2.z, mk2.z, db); db = fmaf(c2.w, mk2.w, db);
      db = fmaf(c3.x, mk3.x, db); db = fmaf(c3.y, mk3.y, db);
      db = fmaf(c3.z, mk3.z, db); db = fmaf(c3.w, mk3.w, db);
      dot = da + db;
    }

    // 5-level butterfly, stays within each 32-lane half (two rows at once)
    #pragma unroll
    for (int m = 1; m < 32; m <<= 1) {
      sq += __shfl_xor(sq, m);
      if constexpr (!INIT) dot += __shfl_xor(dot, m);
    }

    float t = sqrtf(1.0f + sq);
    float w;
    if constexpr (INIT) {
      w = 1.0f;
    } else {
      float a = fmaf(m0, t, -dot);        // -mdot(mean, p)
      float x = fmaxf(a, 1.0f + 1e-5f);
      float s = sqrtf(fmaf(x, x, -1.0f)); // sinh(d)
      float d = logf(x + s);              // arccosh(x)
      w = d / s;                          // d / sinh(d)
      if (sl == 0) acc_cc = fma((double)w, (double)x, acc_cc);
    }
    if (sl == 0) acc_t = fma((double)w, (double)t, acc_t);

    double wd = (double)w;
    acc[0][0] = fma(wd, (double)c0.x, acc[0][0]);
    acc[0][1] = fma(wd, (double)c0.y, acc[0][1]);
    acc[0][2] = fma(wd, (double)c0.z, acc[0][2]);
    acc[0][3] = fma(wd, (double)c0.w, acc[0][3]);
    acc[1][0] = fma(wd, (double)c1v.x, acc[1][0]);
    acc[1][1] = fma(wd, (double)c1v.y, acc[1][1]);
    acc[1][2] = fma(wd, (double)c1v.z, acc[1][2]);
    acc[1][3] = fma(wd, (double)c1v.w, acc[1][3]);
    acc[2][0] = fma(wd, (double)c2.x, acc[2][0]);
    acc[2][1] = fma(wd, (double)c2.y, acc[2][1]);
    acc[2][2] = fma(wd, (double)c2.z, acc[2][2]);
    acc[2][3] = fma(wd, (double)c2.w, acc[2][3]);
    acc[3][0] = fma(wd, (double)c3.x, acc[3][0]);
    acc[3][1] = fma(wd, (double)c3.y, acc[3][1]);
    acc[3][2] = fma(wd, (double)c3.z, acc[3][2]);
    acc[3][3] = fma(wd, (double)c3.w, acc[3][3]);

    if (hasnext) { c0 = n0; c1v = n1; c2 = n2; c3 = n3; }
  }
#undef LDPAIR

  // merge the two halves (same column sets): xor-32 shuffle on f64 accs
  #pragma unroll
  for (int j = 0; j < 4; ++j) {
    #pragma unroll
    for (int i = 0; i < 4; ++i) acc[j][i] += __shfl_xor(acc[j][i], 32);
  }
  acc_t  += __shfl_xor(acc_t, 32);
  acc_cc += __shfl_xor(acc_cc, 32);

  __shared__ double s_red[WPB][514];
  if (half == 0) {
    #pragma unroll
    for (int j = 0; j < 4; ++j) {
      #pragma unroll
      for (int i = 0; i < 4; ++i) s_red[wid][(j*32 + sl)*4 + i] = acc[j][i];
    }
  }
  if (l == 0) { s_red[wid][512] = acc_t; s_red[wid][513] = acc_cc; }
  __syncthreads();

  for (int cc2 = threadIdx.x; cc2 < 514; cc2 += BLK) {
    double s = 0.0;
    #pragma unroll
    for (int w2 = 0; w2 < WPB; ++w2) s += s_red[w2][cc2];
    ws->part[cc2][blockIdx.x] = s;
  }
}

// ---------------- finalize (device): one wave does the exp-map update ----------------
template<bool INIT>
__device__ void finalize_wave(Ws* __restrict__ ws, int l)
{
  double sv[9];
  #pragma unroll
  for (int q = 0; q < 9; ++q) {
    int c = q * 64 + l;
    sv[q] = 0.0;
    if (c < D1) sv[q] = ws->colsum[(c == 0) ? 512 : (c - 1)];
  }

  if constexpr (INIT) {
    double r[9]; double s2 = 0.0;
    #pragma unroll
    for (int q = 0; q < 9; ++q) {
      int c = q * 64 + l;
      r[q] = 0.0;
      if (c < D1) { r[q] = sv[q] / (double)N_PTS; s2 += r[q] * r[q]; }
    }
    #pragma unroll
    for (int m = 1; m < 64; m <<= 1) s2 += __shfl_xor(s2, m);
    double r0 = __shfl(r[0], 0);
    double inv = 1.0 / sqrt(fabs(s2 - 2.0 * r0 * r0));
    #pragma unroll
    for (int q = 0; q < 9; ++q) {
      int c = q * 64 + l;
      if (c < D1) ws->mean[c] = (float)(r[q] * inv);
    }
  } else {
    double cc = ws->colsum[513];
    double mv[9], yv[9]; double sy = 0.0;
    #pragma unroll
    for (int q = 0; q < 9; ++q) {
      int c = q * 64 + l;
      mv[q] = 0.0; yv[q] = 0.0;
      if (c < D1) {
        double m = (double)ws->mean[c];
        double y = 0.02 * (sv[q] - cc * m) / (double)N_PTS;  // y = -R*g, R=0.01
        mv[q] = m; yv[q] = y;
        sy += y * y;
      }
    }
    #pragma unroll
    for (int m = 1; m < 64; m <<= 1) sy += __shfl_xor(sy, m);
    double y0 = __shfl(yv[0], 0);
    double n = sqrt(fabs(sy - 2.0 * y0 * y0));
    n = fmax(n, 1e-5);
    double ch = cosh(n);
    double sn = (n < 1e-4) ? (1.0 + n * n / 6.0) : (sinh(n) / n);
    double nm[9]; double s2 = 0.0;
    #pragma unroll
    for (int q = 0; q < 9; ++q) {
      int c = q * 64 + l;
      nm[q] = 0.0;
      if (c < D1) { nm[q] = ch * mv[q] + sn * yv[q]; s2 += nm[q] * nm[q]; }
    }
    #pragma unroll
    for (int m = 1; m < 64; m <<= 1) s2 += __shfl_xor(s2, m);
    double m0n = __shfl(nm[0], 0);
    double inv = 1.0 / sqrt(fabs(s2 - 2.0 * m0n * m0n));
    #pragma unroll
    for (int q = 0; q < 9; ++q) {
      int c = q * 64 + l;
      if (c < D1) ws->mean[c] = (float)(nm[q] * inv);
    }
  }
}

// ---------------- per-column reduce + fused finalize (ticketed last block) ----------------
template<bool INIT>
__global__ __launch_bounds__(64)
void colreduce_kernel(Ws* __restrict__ ws)
{
  const int c = blockIdx.x;       // 0..513
  const int l = threadIdx.x;
  const double* col = ws->part[c];
  double s = 0.0;
  #pragma unroll
  for (int k = 0; k < GRID / 64; ++k) s += col[l + 64 * k];
  #pragma unroll
  for (int m = 1; m < 64; m <<= 1) s += __shfl_xor(s, m);
  if (l == 0) ws->colsum[c] = s;

  // ticket: last block to finish runs the exp-map update
  __shared__ unsigned int s_t;
  __threadfence();                               // release colsum write
  if (l == 0) s_t = atomicAdd(&ws->ticket, 1u);
  __syncthreads();
  if (s_t == 513u) {
    __threadfence();                             // acquire all colsum writes
    finalize_wave<INIT>(ws, l);
    if (l == 0) ws->ticket = 0u;                 // reset for next iteration/replay
  }
}

__global__ void write_out_kernel(const float* __restrict__ mean, float* __restrict__ out)
{
  int i = threadIdx.x;
  if (i < SDIM) out[i] = mean[1 + i];
}

extern "C" void kernel_launch(void* const* d_in, const int* in_sizes, int n_in,
                              void* d_out, int out_size, void* d_ws, size_t ws_size,
                              hipStream_t stream)
{
  (void)in_sizes; (void)n_in; (void)out_size; (void)ws_size;
  const float* data = (const float*)d_in[0];
  Ws* ws = (Ws*)d_ws;

  // zero the ticket (everything else is fully overwritten each pass)
  hipMemsetAsync(d_ws, 0, 16, stream);

  // init: mean = normalize(mean over N of projected)
  big_kernel<true><<<dim3(GRID), dim3(BLK), 0, stream>>>(data, ws, 0);
  colreduce_kernel<true><<<dim3(514), dim3(64), 0, stream>>>(ws);

  for (int it = 0; it < NITER; ++it) {
    big_kernel<false><<<dim3(GRID), dim3(BLK), 0, stream>>>(data, ws, (it & 1) ^ 1);
    colreduce_kernel<false><<<dim3(514), dim3(64), 0, stream>>>(ws);
  }

  float* meanp = (float*)((char*)d_ws + offsetof(Ws, mean));
  write_out_kernel<<<dim3(1), dim3(512), 0, stream>>>(meanp, (float*)d_out);
}

// Round 8
// 6194.955 us; speedup vs baseline: 1.2237x; 1.2237x over previous
//
#include <hip/hip_runtime.h>
#include <math.h>
#include <cstddef>

#define N_PTS 131072
#define SDIM  512
#define D1    513

static constexpr int NITER = 100;
static constexpr int BLK   = 512;            // 8 waves / block
static constexpr int GRID  = 512;            // 2 blocks / CU
static constexpr int WPB   = BLK / 64;       // 8 waves per block
static constexpr int NW    = GRID * WPB;     // 4096 waves
static constexpr int NPAIR = N_PTS / 2;      // 65536 row-pairs
static constexpr int PPW   = NPAIR / NW;     // 16 pairs per wave

struct Ws {
  double colsum[514];          // [0..511] spatial, [512] t-sum, [513] cc-sum
  double part[514][GRID];      // column-major per-block partials
  float  mean[513];            // [0] = time coordinate
};

// ---------------- streaming kernel: 2 pairs (4 rows) per loop iteration ----------------
// Named register sets (compile-time indices only). 4 independent reduction
// chains interleave; 8 loads in flight issued 2 pairs ahead. f32 weighted
// accumulators (error << threshold; cross-wave combine stays f64).
template<bool INIT>
__global__ __launch_bounds__(BLK, 4)
void big_kernel(const float* __restrict__ data, Ws* __restrict__ ws, int rev)
{
  const int l    = threadIdx.x & 63;
  const int sl   = l & 31;       // lane within half
  const int half = l >> 5;       // 0: even row of pair, 1: odd row
  const int wid  = threadIdx.x >> 6;
  const int gw   = blockIdx.x * WPB + wid;   // 0..NW-1

  float  m0 = 0.f;
  float4 mk0 = {0,0,0,0}, mk1 = {0,0,0,0}, mk2 = {0,0,0,0}, mk3 = {0,0,0,0};
  if constexpr (!INIT) {
    m0 = ws->mean[0];
    const float4* mp = (const float4*)(ws->mean + 1);
    mk0 = mp[0*32 + sl]; mk1 = mp[1*32 + sl];
    mk2 = mp[2*32 + sl]; mk3 = mp[3*32 + sl];
  }

  // f32 weighted accumulators; lane covers cols (j*32+sl)*4 + i
  float accf[4][4] = {};
  double acc_t = 0.0, acc_cc = 0.0;

  const int p0 = gw * PPW;

#define LDP(R, p) do {                                                        \
    int pr_ = rev ? (NPAIR - 1 - (p)) : (p);                                  \
    const float4* b_ = (const float4*)(data + (size_t)(2 * pr_ + half) * SDIM); \
    R##0 = b_[0*32 + sl]; R##1 = b_[1*32 + sl];                               \
    R##2 = b_[2*32 + sl]; R##3 = b_[3*32 + sl];                               \
  } while (0)

  float4 A0, A1, A2, A3, B0, B1, B2, B3, P0, P1, P2, P3, Q0, Q1, Q2, Q3;
  LDP(A, p0 + 0);
  LDP(B, p0 + 1);

  for (int kk = 0; kk < PPW; kk += 2) {
    const bool more = (kk + 2 < PPW);
    if (more) { LDP(P, p0 + kk + 2); LDP(Q, p0 + kk + 3); }

    // per-lane partial sums: two independent trees per pair
    float sqA = A0.x * A0.x;
    sqA = fmaf(A0.y, A0.y, sqA); sqA = fmaf(A0.z, A0.z, sqA); sqA = fmaf(A0.w, A0.w, sqA);
    sqA = fmaf(A1.x, A1.x, sqA); sqA = fmaf(A1.y, A1.y, sqA);
    sqA = fmaf(A1.z, A1.z, sqA); sqA = fmaf(A1.w, A1.w, sqA);
    float sqA2 = A2.x * A2.x;
    sqA2 = fmaf(A2.y, A2.y, sqA2); sqA2 = fmaf(A2.z, A2.z, sqA2); sqA2 = fmaf(A2.w, A2.w, sqA2);
    sqA2 = fmaf(A3.x, A3.x, sqA2); sqA2 = fmaf(A3.y, A3.y, sqA2);
    sqA2 = fmaf(A3.z, A3.z, sqA2); sqA2 = fmaf(A3.w, A3.w, sqA2);
    sqA += sqA2;

    float sqB = B0.x * B0.x;
    sqB = fmaf(B0.y, B0.y, sqB); sqB = fmaf(B0.z, B0.z, sqB); sqB = fmaf(B0.w, B0.w, sqB);
    sqB = fmaf(B1.x, B1.x, sqB); sqB = fmaf(B1.y, B1.y, sqB);
    sqB = fmaf(B1.z, B1.z, sqB); sqB = fmaf(B1.w, B1.w, sqB);
    float sqB2 = B2.x * B2.x;
    sqB2 = fmaf(B2.y, B2.y, sqB2); sqB2 = fmaf(B2.z, B2.z, sqB2); sqB2 = fmaf(B2.w, B2.w, sqB2);
    sqB2 = fmaf(B3.x, B3.x, sqB2); sqB2 = fmaf(B3.y, B3.y, sqB2);
    sqB2 = fmaf(B3.z, B3.z, sqB2); sqB2 = fmaf(B3.w, B3.w, sqB2);
    sqB += sqB2;

    float dotA = 0.f, dotB = 0.f;
    if constexpr (!INIT) {
      float dA = A0.x * mk0.x;
      dA = fmaf(A0.y, mk0.y, dA); dA = fmaf(A0.z, mk0.z, dA); dA = fmaf(A0.w, mk0.w, dA);
      dA = fmaf(A1.x, mk1.x, dA); dA = fmaf(A1.y, mk1.y, dA);
      dA = fmaf(A1.z, mk1.z, dA); dA = fmaf(A1.w, mk1.w, dA);
      float dA2 = A2.x * mk2.x;
      dA2 = fmaf(A2.y, mk2.y, dA2); dA2 = fmaf(A2.z, mk2.z, dA2); dA2 = fmaf(A2.w, mk2.w, dA2);
      dA2 = fmaf(A3.x, mk3.x, dA2); dA2 = fmaf(A3.y, mk3.y, dA2);
      dA2 = fmaf(A3.z, mk3.z, dA2); dA2 = fmaf(A3.w, mk3.w, dA2);
      dotA = dA + dA2;

      float dB = B0.x * mk0.x;
      dB = fmaf(B0.y, mk0.y, dB); dB = fmaf(B0.z, mk0.z, dB); dB = fmaf(B0.w, mk0.w, dB);
      dB = fmaf(B1.x, mk1.x, dB); dB = fmaf(B1.y, mk1.y, dB);
      dB = fmaf(B1.z, mk1.z, dB); dB = fmaf(B1.w, mk1.w, dB);
      float dB2 = B2.x * mk2.x;
      dB2 = fmaf(B2.y, mk2.y, dB2); dB2 = fmaf(B2.z, mk2.z, dB2); dB2 = fmaf(B2.w, mk2.w, dB2);
      dB2 = fmaf(B3.x, mk3.x, dB2); dB2 = fmaf(B3.y, mk3.y, dB2);
      dB2 = fmaf(B3.z, mk3.z, dB2); dB2 = fmaf(B3.w, mk3.w, dB2);
      dotB = dB + dB2;
    }

    // 5-level butterfly within each 32-lane half; 4 independent chains interleave
    #pragma unroll
    for (int m = 1; m < 32; m <<= 1) {
      sqA += __shfl_xor(sqA, m);
      sqB += __shfl_xor(sqB, m);
      if constexpr (!INIT) {
        dotA += __shfl_xor(dotA, m);
        dotB += __shfl_xor(dotB, m);
      }
    }

    float tA = sqrtf(1.0f + sqA);
    float tB = sqrtf(1.0f + sqB);
    float wA, wB;
    if constexpr (INIT) {
      wA = 1.0f; wB = 1.0f;
      if (sl == 0) acc_t += (double)tA + (double)tB;
    } else {
      float aA = fmaf(m0, tA, -dotA);
      float aB = fmaf(m0, tB, -dotB);
      float xA = fmaxf(aA, 1.0f + 1e-5f);
      float xB = fmaxf(aB, 1.0f + 1e-5f);
      float sA = sqrtf(fmaf(xA, xA, -1.0f));
      float sB = sqrtf(fmaf(xB, xB, -1.0f));
      float dA = logf(xA + sA);
      float dB = logf(xB + sB);
      wA = dA / sA;
      wB = dB / sB;
      if (sl == 0) {
        acc_cc += fma((double)wA, (double)xA, (double)wB * (double)xB);
        acc_t  += fma((double)wA, (double)tA, (double)wB * (double)tB);
      }
    }

    // f32 weighted accumulation, both pairs fused
    accf[0][0] = fmaf(wA, A0.x, fmaf(wB, B0.x, accf[0][0]));
    accf[0][1] = fmaf(wA, A0.y, fmaf(wB, B0.y, accf[0][1]));
    accf[0][2] = fmaf(wA, A0.z, fmaf(wB, B0.z, accf[0][2]));
    accf[0][3] = fmaf(wA, A0.w, fmaf(wB, B0.w, accf[0][3]));
    accf[1][0] = fmaf(wA, A1.x, fmaf(wB, B1.x, accf[1][0]));
    accf[1][1] = fmaf(wA, A1.y, fmaf(wB, B1.y, accf[1][1]));
    accf[1][2] = fmaf(wA, A1.z, fmaf(wB, B1.z, accf[1][2]));
    accf[1][3] = fmaf(wA, A1.w, fmaf(wB, B1.w, accf[1][3]));
    accf[2][0] = fmaf(wA, A2.x, fmaf(wB, B2.x, accf[2][0]));
    accf[2][1] = fmaf(wA, A2.y, fmaf(wB, B2.y, accf[2][1]));
    accf[2][2] = fmaf(wA, A2.z, fmaf(wB, B2.z, accf[2][2]));
    accf[2][3] = fmaf(wA, A2.w, fmaf(wB, B2.w, accf[2][3]));
    accf[3][0] = fmaf(wA, A3.x, fmaf(wB, B3.x, accf[3][0]));
    accf[3][1] = fmaf(wA, A3.y, fmaf(wB, B3.y, accf[3][1]));
    accf[3][2] = fmaf(wA, A3.z, fmaf(wB, B3.z, accf[3][2]));
    accf[3][3] = fmaf(wA, A3.w, fmaf(wB, B3.w, accf[3][3]));

    if (more) {
      A0 = P0; A1 = P1; A2 = P2; A3 = P3;
      B0 = Q0; B1 = Q1; B2 = Q2; B3 = Q3;
    }
  }
#undef LDP

  // merge the two halves (same column sets): xor-32 shuffle
  #pragma unroll
  for (int j = 0; j < 4; ++j) {
    #pragma unroll
    for (int i = 0; i < 4; ++i) accf[j][i] += __shfl_xor(accf[j][i], 32);
  }
  acc_t  += __shfl_xor(acc_t, 32);
  acc_cc += __shfl_xor(acc_cc, 32);

  __shared__ double s_red[WPB][514];
  if (half == 0) {
    #pragma unroll
    for (int j = 0; j < 4; ++j) {
      #pragma unroll
      for (int i = 0; i < 4; ++i) s_red[wid][(j*32 + sl)*4 + i] = (double)accf[j][i];
    }
  }
  if (l == 0) { s_red[wid][512] = acc_t; s_red[wid][513] = acc_cc; }
  __syncthreads();

  for (int c = threadIdx.x; c < 514; c += BLK) {
    double s = 0.0;
    #pragma unroll
    for (int w2 = 0; w2 < WPB; ++w2) s += s_red[w2][c];
    ws->part[c][blockIdx.x] = s;
  }
}

// ---------------- per-column reduce: one wave per column ----------------
__global__ __launch_bounds__(64)
void colreduce_kernel(Ws* __restrict__ ws)
{
  const int c = blockIdx.x;       // 0..513
  const int l = threadIdx.x;
  const double* col = ws->part[c];
  double s = 0.0;
  #pragma unroll
  for (int k = 0; k < GRID / 64; ++k) s += col[l + 64 * k];
  #pragma unroll
  for (int m = 1; m < 64; m <<= 1) s += __shfl_xor(s, m);
  if (l == 0) ws->colsum[c] = s;
}

// ---------------- finalize: one wave does the exp-map update ----------------
template<bool INIT>
__global__ __launch_bounds__(64)
void finalize_kernel(Ws* __restrict__ ws)
{
  const int l = threadIdx.x;
  double sv[9];
  #pragma unroll
  for (int q = 0; q < 9; ++q) {
    int c = q * 64 + l;
    sv[q] = 0.0;
    if (c < D1) sv[q] = ws->colsum[(c == 0) ? 512 : (c - 1)];
  }

  if constexpr (INIT) {
    double r[9]; double s2 = 0.0;
    #pragma unroll
    for (int q = 0; q < 9; ++q) {
      int c = q * 64 + l;
      r[q] = 0.0;
      if (c < D1) { r[q] = sv[q] / (double)N_PTS; s2 += r[q] * r[q]; }
    }
    #pragma unroll
    for (int m = 1; m < 64; m <<= 1) s2 += __shfl_xor(s2, m);
    double r0 = __shfl(r[0], 0);
    double inv = 1.0 / sqrt(fabs(s2 - 2.0 * r0 * r0));
    #pragma unroll
    for (int q = 0; q < 9; ++q) {
      int c = q * 64 + l;
      if (c < D1) ws->mean[c] = (float)(r[q] * inv);
    }
  } else {
    double cc = ws->colsum[513];
    double mv[9], yv[9]; double sy = 0.0;
    #pragma unroll
    for (int q = 0; q < 9; ++q) {
      int c = q * 64 + l;
      mv[q] = 0.0; yv[q] = 0.0;
      if (c < D1) {
        double m = (double)ws->mean[c];
        double y = 0.02 * (sv[q] - cc * m) / (double)N_PTS;  // y = -R*g, R=0.01
        mv[q] = m; yv[q] = y;
        sy += y * y;
      }
    }
    #pragma unroll
    for (int m = 1; m < 64; m <<= 1) sy += __shfl_xor(sy, m);
    double y0 = __shfl(yv[0], 0);
    double n = sqrt(fabs(sy - 2.0 * y0 * y0));
    n = fmax(n, 1e-5);
    double ch = cosh(n);
    double sn = (n < 1e-4) ? (1.0 + n * n / 6.0) : (sinh(n) / n);
    double nm[9]; double s2 = 0.0;
    #pragma unroll
    for (int q = 0; q < 9; ++q) {
      int c = q * 64 + l;
      nm[q] = 0.0;
      if (c < D1) { nm[q] = ch * mv[q] + sn * yv[q]; s2 += nm[q] * nm[q]; }
    }
    #pragma unroll
    for (int m = 1; m < 64; m <<= 1) s2 += __shfl_xor(s2, m);
    double m0n = __shfl(nm[0], 0);
    double inv = 1.0 / sqrt(fabs(s2 - 2.0 * m0n * m0n));
    #pragma unroll
    for (int q = 0; q < 9; ++q) {
      int c = q * 64 + l;
      if (c < D1) ws->mean[c] = (float)(nm[q] * inv);
    }
  }
}

__global__ void write_out_kernel(const float* __restrict__ mean, float* __restrict__ out)
{
  int i = threadIdx.x;
  if (i < SDIM) out[i] = mean[1 + i];
}

extern "C" void kernel_launch(void* const* d_in, const int* in_sizes, int n_in,
                              void* d_out, int out_size, void* d_ws, size_t ws_size,
                              hipStream_t stream)
{
  (void)in_sizes; (void)n_in; (void)out_size; (void)ws_size;
  const float* data = (const float*)d_in[0];
  Ws* ws = (Ws*)d_ws;

  // init: mean = normalize(mean over N of projected). No memset needed:
  // part/colsum/mean are fully overwritten before any read each pass.
  big_kernel<true><<<dim3(GRID), dim3(BLK), 0, stream>>>(data, ws, 0);
  colreduce_kernel<<<dim3(514), dim3(64), 0, stream>>>(ws);
  finalize_kernel<true><<<dim3(1), dim3(64), 0, stream>>>(ws);

  for (int it = 0; it < NITER; ++it) {
    big_kernel<false><<<dim3(GRID), dim3(BLK), 0, stream>>>(data, ws, (it & 1) ^ 1);
    colreduce_kernel<<<dim3(514), dim3(64), 0, stream>>>(ws);
    finalize_kernel<false><<<dim3(1), dim3(64), 0, stream>>>(ws);
  }

  float* meanp = (float*)((char*)d_ws + offsetof(Ws, mean));
  write_out_kernel<<<dim3(1), dim3(512), 0, stream>>>(meanp, (float*)d_out);
}